// Round 1
// baseline (504.994 us; speedup 1.0000x reference)
//
#include <hip/hip_runtime.h>
#include <math.h>

#define NPROP 2000
#define PANELTY_K 0.055f
#define HANN_W 0.42f
#define PI_F 3.14159265358979323846f

// One block per row. 256 threads stride the 2000 proposals.
// Memory-bound: ~459 MB streamed once; target ~73 us at 6.3 TB/s.
__global__ __launch_bounds__(256) void trnms_kernel(
    const float* __restrict__ rois,      // (N,4)
    const float* __restrict__ rpn,       // (N,NPROP,5)
    const float* __restrict__ scores,    // (N,NPROP,2)
    float* __restrict__ out_rois,        // (N,4)
    float* __restrict__ out_scores)      // (N,1)
{
    const int i   = blockIdx.x;
    const int tid = threadIdx.x;

    // Reference ROI stats (identical expression order to the numpy reference)
    const float rx1 = rois[i * 4 + 0], ry1 = rois[i * 4 + 1];
    const float rx2 = rois[i * 4 + 2], ry2 = rois[i * 4 + 3];
    const float x = (rx1 + rx2) * 0.5f;
    const float y = (ry1 + ry2) * 0.5f;
    const float w = fabsf(rx1 - rx2) + 0.0001f;
    const float h = fabsf(ry1 - ry2) + 0.0001f;
    const float p = (w + h) * 0.5f;
    const float s = sqrtf((w + p) * (h + p));
    const float ratio = w / h;
    const float r_max = fmaxf(ratio, 1.0f / ratio);
    const float window = s * 2.0f;  // HANNING_WINDOW_SIZE_FACTOR

    const float* __restrict__ rowr  = rpn    + (long long)i * (NPROP * 5);
    const float* __restrict__ rowsc = scores + (long long)i * (NPROP * 2);

    float best  = -INFINITY;
    int   besti = 0x7fffffff;

    for (int j = tid; j < NPROP; j += 256) {
        const float px1 = rowr[j * 5 + 1];
        const float py1 = rowr[j * 5 + 2];
        const float px2 = rowr[j * 5 + 3];
        const float py2 = rowr[j * 5 + 4];
        const float x_ = (px1 + px2) * 0.5f;
        const float y_ = (py1 + py2) * 0.5f;
        const float w_ = fabsf(px1 - px2) + 0.0001f;
        const float h_ = fabsf(py1 - py2) + 0.0001f;
        const float p_ = (w_ + h_) * 0.5f;
        const float s_ = sqrtf((w_ + p_) * (h_ + p_));
        const float smax = fmaxf(s / s_, s_ / s);
        const float pen  = expf(-PANELTY_K * (smax * r_max - 1.0f));
        const float dx = x - x_;
        const float dy = y - y_;
        const float dist = sqrtf(dx * dx + dy * dy);
        float han = 0.5f + 0.5f * cosf(dist * PI_F / window);
        han = (dist > window) ? 0.0f : han;
        const float val = rowsc[j * 2 + 1] * pen + han * HANN_W;
        // strict > keeps the earliest j within this thread's increasing sequence
        if (val > best || (val == best && j < besti)) { best = val; besti = j; }
    }

    // Wave-level reduction (64 lanes), first-index tie-break
    #pragma unroll
    for (int off = 32; off > 0; off >>= 1) {
        const float ov = __shfl_down(best, off);
        const int   oi = __shfl_down(besti, off);
        if (ov > best || (ov == best && oi < besti)) { best = ov; besti = oi; }
    }

    __shared__ float sval[4];
    __shared__ int   sidx[4];
    const int wave = tid >> 6;
    if ((tid & 63) == 0) { sval[wave] = best; sidx[wave] = besti; }
    __syncthreads();

    if (tid == 0) {
        #pragma unroll
        for (int k = 1; k < 4; ++k) {
            const float ov = sval[k];
            const int   oi = sidx[k];
            if (ov > best || (ov == best && oi < besti)) { best = ov; besti = oi; }
        }
        out_rois[i * 4 + 0] = rowr[besti * 5 + 1];
        out_rois[i * 4 + 1] = rowr[besti * 5 + 2];
        out_rois[i * 4 + 2] = rowr[besti * 5 + 3];
        out_rois[i * 4 + 3] = rowr[besti * 5 + 4];
        out_scores[i] = rowsc[besti * 2 + 1];
    }
}

extern "C" void kernel_launch(void* const* d_in, const int* in_sizes, int n_in,
                              void* d_out, int out_size, void* d_ws, size_t ws_size,
                              hipStream_t stream) {
    const float* rois   = (const float*)d_in[0];  // (N,4)
    const float* rpn    = (const float*)d_in[1];  // (N,2000,5)
    const float* scores = (const float*)d_in[2];  // (N,2000,2)

    const int N = in_sizes[0] / 4;  // 8192

    float* out_rois   = (float*)d_out;          // first N*4 floats
    float* out_scores = (float*)d_out + N * 4;  // next N floats

    trnms_kernel<<<N, 256, 0, stream>>>(rois, rpn, scores, out_rois, out_scores);
}